// Round 2
// 121.818 us; speedup vs baseline: 1.0099x; 1.0099x over previous
//
#include <hip/hip_runtime.h>
#include <math.h>

// EnhancedTripletLoss, B=8192, D=256, 8 classes.
// R18 = R17 with the DPP reduction direction bug fixed.
//  - row_shr:N moves data toward HIGHER lanes (lane i <- lane i-N), so the
//    16-lane max/min butterfly accumulates into l15==15, not l15==0.
//    R17 published from l15==0 (unreduced garbage). Publish from l15==15.
//  - Rest identical to R17: no A-LDS (A fragments read from L2, layout is
//    fragment-major), 256-thread half-blocks (grid 4160) to kill 8-wave
//    occupancy quantization, __launch_bounds__(256,6), DPP i-side reduce.
//  - Slot scheme: i-side slot 2*bj+wj, j-side slot 2*bi+hb; all 128 slots
//    written exactly once per anchor; k_finish unchanged (R15's proven form).

typedef __attribute__((ext_vector_type(8))) short short8;
typedef __attribute__((ext_vector_type(4))) float floatx4;

#define B_N 8192
#define D_K 256

__device__ __forceinline__ unsigned short f2bf_rne(float f) {
  unsigned u = __float_as_uint(f);
  u += 0x7FFFu + ((u >> 16) & 1u);
  return (unsigned short)(u >> 16);
}

// DPP helper: row_shr:N — lane i gets lane i-N within its 16-lane row; lanes
// with out-of-row source keep x (old), which is identity for max/min.
#define DPP_SHR(x, CTRL) \
  ((unsigned)__builtin_amdgcn_update_dpp((int)(x), (int)(x), (CTRL), 0xF, 0xF, false))

// ---- split to bf16 fragment-major + quantized row norms ----
// Tile (16 rows x 32 k) = 512 ushorts at [tile_row][tk][lane*8+j]:
// lane = quad*16 + m, row = 16*tile_row + m, k = 32*tk + quad*8 + j.
__global__ void k_split(const float* __restrict__ x, unsigned short* __restrict__ xhf,
                        float* __restrict__ sqq,
                        float* __restrict__ sum, int* __restrict__ cnt,
                        int* __restrict__ done) {
  __shared__ float sw[64];
  const int tid  = threadIdx.x;
  const int lane = tid & 63;
  const int w    = tid >> 6;
  const int b    = blockIdx.x;        // tile_row
  const int m    = lane & 15;
  const int quad = lane >> 4;
  const int row  = b * 16 + m;

  float s = 0.f;
#pragma unroll
  for (int h = 0; h < 2; ++h) {
    int tk = w + h * 4;
    int kk = tk * 32 + quad * 8;
    float4 f0 = *reinterpret_cast<const float4*>(x + (size_t)row * D_K + kk);
    float4 f1 = *reinterpret_cast<const float4*>(x + (size_t)row * D_K + kk + 4);
    s += f0.x * f0.x + f0.y * f0.y + f0.z * f0.z + f0.w * f0.w;
    s += f1.x * f1.x + f1.y * f1.y + f1.z * f1.z + f1.w * f1.w;
    ushort4 lo, hi;
    lo.x = f2bf_rne(f0.x); lo.y = f2bf_rne(f0.y); lo.z = f2bf_rne(f0.z); lo.w = f2bf_rne(f0.w);
    hi.x = f2bf_rne(f1.x); hi.y = f2bf_rne(f1.y); hi.z = f2bf_rne(f1.z); hi.w = f2bf_rne(f1.w);
    size_t o = ((size_t)b * 8 + tk) * 512 + lane * 8;
    *reinterpret_cast<ushort4*>(xhf + o)     = lo;
    *reinterpret_cast<ushort4*>(xhf + o + 4) = hi;
  }
  s += __shfl_xor(s, 16);
  s += __shfl_xor(s, 32);
  if (quad == 0) sw[w * 16 + m] = s;
  __syncthreads();
  if (tid < 16) {
    int i = b * 16 + tid;
    float t = sw[tid] + sw[16 + tid] + sw[32 + tid] + sw[48 + tid];
    sqq[i] = fmaf(t, 128.f, 262144.f);   // pre-quantized for key calc
  }
  if (b == 0 && tid == 0) { *sum = 0.f; *cnt = 0; *done = 0; }
}

// ---- MFMA Gram + two-sided mining, 4 waves/block (half-tiles), no A-LDS ----
__global__ __launch_bounds__(256, 6) void k_mine16(
    const unsigned short* __restrict__ xhf, const int* __restrict__ lab,
    const float* __restrict__ sqq,
    unsigned* __restrict__ ppart, unsigned* __restrict__ npart) {
  __shared__ unsigned jbp[4 * 64], jbn[4 * 64];  // 2 KB: per-wave j-side partials

  // decode linear block id -> (bi, bj, half); bi <= bj over 64x64 super-tiles
  int t  = blockIdx.x;
  const int hb = t & 1;               // which 64-row half of the 128-row band
  t >>= 1;
  int bi = (int)(64.5f - sqrtf(64.5f * 64.5f - 2.f * (float)t));
  int b0 = 64 * bi - (bi * (bi - 1)) / 2;
  if (t < b0) { bi--; b0 = 64 * bi - (bi * (bi - 1)) / 2; }
  else {
    int b1 = 64 * (bi + 1) - ((bi + 1) * bi) / 2;
    if (t >= b1) { bi++; b0 = b1; }
  }
  const int bj = bi + (t - b0);

  const int tid  = threadIdx.x;
  const int lane = tid & 63;
  const int w    = tid >> 6;          // 0..3
  const int wi   = w >> 1;            // 0..1 : 32-anchor band within the half
  const int wj   = w & 1;             // 0..1 : 64-j half
  const int quad = lane >> 4, l15 = lane & 15;
  const int i0   = bi * 128 + hb * 64 + wi * 32;

  unsigned lip = 0;
  float    sqi[8];
#pragma unroll
  for (int r = 0; r < 8; ++r) {
    int ir = i0 + (r >> 2) * 16 + quad * 4 + (r & 3);
    lip |= ((unsigned)lab[ir] & 0xFu) << (r * 4);
    sqi[r] = sqq[ir];
  }

  // fragment-major offsets (ushort units): row-block rb -> rb*4096 + tk*512
  const unsigned aoff = (unsigned)(i0 >> 4) * 4096u + (unsigned)lane * 8u;
  const unsigned boff = (unsigned)(bj * 8 + wj * 4) * 4096u + (unsigned)lane * 8u;

  floatx4 acc[8];
#pragma unroll
  for (int q = 0; q < 8; ++q) acc[q] = (floatx4)0.f;

#pragma unroll
  for (int tk = 0; tk < 8; ++tk) {
    short8 Bf[4];
#pragma unroll
    for (int nt = 0; nt < 4; ++nt)
      Bf[nt] = *reinterpret_cast<const short8*>(xhf + boff + (unsigned)(nt * 4096 + tk * 512));
    short8 Af[2];
#pragma unroll
    for (int mt = 0; mt < 2; ++mt)
      Af[mt] = *reinterpret_cast<const short8*>(xhf + aoff + (unsigned)(mt * 4096 + tk * 512));
#pragma unroll
    for (int mt = 0; mt < 2; ++mt)
#pragma unroll
      for (int nt = 0; nt < 4; ++nt)
        acc[mt * 4 + nt] = __builtin_amdgcn_mfma_f32_16x16x32_bf16(
            Af[mt], Bf[nt], acc[mt * 4 + nt], 0, 0, 0);
  }

  // two-sided selection epilogue (keys as in R11/R15).
  // i-side: v_ij = sq_j - 2*dot -> key (cvt(sjq-256*dot)<<13)|j, umax/umin.
  // j-side: v_ji = sq_i - 2*dot -> key (cvt(sqi-256*dot)<<13)|i, same eq.
  unsigned pkey[8], nkey[8];
#pragma unroll
  for (int r = 0; r < 8; ++r) { pkey[r] = 0u; nkey[r] = 0xFFFFFFFFu; }

#pragma unroll
  for (int nt = 0; nt < 4; ++nt) {
    int      j  = bj * 128 + wj * 64 + nt * 16 + l15;
    unsigned jl = (unsigned)lab[j] & 0xFu;
    float    sj = sqq[j];
    unsigned jp = 0u, jn = 0xFFFFFFFFu;
#pragma unroll
    for (int r = 0; r < 8; ++r) {
      float dot = acc[(r >> 2) * 4 + nt][r & 3];
      int   ir  = i0 + (r >> 2) * 16 + quad * 4 + (r & 3);
      bool  eq  = (jl == ((lip >> (r * 4)) & 0xFu));
      // i-side
      unsigned kqi  = (unsigned)fmaf(-256.f, dot, sj);
      unsigned keyi = (kqi << 13) | (unsigned)j;
      unsigned pci = eq ? keyi : 0u;
      unsigned nci = eq ? 0xFFFFFFFFu : keyi;
      pkey[r] = pkey[r] > pci ? pkey[r] : pci;
      nkey[r] = nkey[r] < nci ? nkey[r] : nci;
      // j-side
      unsigned kqj  = (unsigned)fmaf(-256.f, dot, sqi[r]);
      unsigned keyj = (kqj << 13) | (unsigned)ir;
      unsigned pcj = eq ? keyj : 0u;
      unsigned ncj = eq ? 0xFFFFFFFFu : keyj;
      jp = jp > pcj ? jp : pcj;
      jn = jn < ncj ? jn : ncj;
    }
    // reduce j-side across the 4 quads sharing this j, park in LDS
#pragma unroll
    for (int m = 16; m < 64; m <<= 1) {
      unsigned op = (unsigned)__shfl_xor((int)jp, m);
      unsigned on = (unsigned)__shfl_xor((int)jn, m);
      jp = jp > op ? jp : op;
      jn = jn < on ? jn : on;
    }
    if (quad == 0) {
      jbp[w * 64 + nt * 16 + l15] = jp;
      jbn[w * 64 + nt * 16 + l15] = jn;
    }
  }

  // i-side: reduce across the 16 l15-lanes with DPP row_shr butterfly.
  // row_shr:N = lane i <- lane i-N, so the reduction accumulates into the
  // TOP lane of each 16-lane row (l15==15). Step-major over 16 independent
  // chains -> dependency distance 16 instructions.
#pragma unroll
  for (int r = 0; r < 8; ++r) {
    unsigned tp = DPP_SHR(pkey[r], 0x118); pkey[r] = pkey[r] > tp ? pkey[r] : tp;
    unsigned tn = DPP_SHR(nkey[r], 0x118); nkey[r] = nkey[r] < tn ? nkey[r] : tn;
  }
#pragma unroll
  for (int r = 0; r < 8; ++r) {
    unsigned tp = DPP_SHR(pkey[r], 0x114); pkey[r] = pkey[r] > tp ? pkey[r] : tp;
    unsigned tn = DPP_SHR(nkey[r], 0x114); nkey[r] = nkey[r] < tn ? nkey[r] : tn;
  }
#pragma unroll
  for (int r = 0; r < 8; ++r) {
    unsigned tp = DPP_SHR(pkey[r], 0x112); pkey[r] = pkey[r] > tp ? pkey[r] : tp;
    unsigned tn = DPP_SHR(nkey[r], 0x112); nkey[r] = nkey[r] < tn ? nkey[r] : tn;
  }
#pragma unroll
  for (int r = 0; r < 8; ++r) {
    unsigned tp = DPP_SHR(pkey[r], 0x111); pkey[r] = pkey[r] > tp ? pkey[r] : tp;
    unsigned tn = DPP_SHR(nkey[r], 0x111); nkey[r] = nkey[r] < tn ? nkey[r] : tn;
  }
#pragma unroll
  for (int r = 0; r < 8; ++r) {
    if (l15 == 15) {                     // reduction lands in the top lane
      int ir = i0 + (r >> 2) * 16 + quad * 4 + (r & 3);
      size_t idx = (size_t)(2 * bj + wj) * B_N + ir;
      ppart[idx] = pkey[r];
      npart[idx] = nkey[r];
    }
  }

  __syncthreads();
  // j-side combine across the wi-pair sharing wj: waves w in {0,1} merge with
  // w+2 and publish slot 2*bi + hb of band bj. Diagonal skipped (i-side covers).
  if (wi == 0 && bi != bj) {
    unsigned p  = jbp[w * 64 + lane];
    unsigned n  = jbn[w * 64 + lane];
    unsigned p2 = jbp[(w + 2) * 64 + lane];
    unsigned n2 = jbn[(w + 2) * 64 + lane];
    p = p > p2 ? p : p2;
    n = n < n2 ? n : n2;
    int j = bj * 128 + wj * 64 + lane;
    size_t idx = (size_t)(2 * bi + hb) * B_N + j;
    ppart[idx] = p;
    npart[idx] = n;
  }
}

// ---- slot-reduce + exact fp32 triplet distances + loss (R15's proven form) ----
__global__ void k_finish(const float* __restrict__ x,
                         const unsigned* __restrict__ ppart,
                         const unsigned* __restrict__ npart,
                         float* __restrict__ sum, int* __restrict__ cnt,
                         int* __restrict__ done, float* __restrict__ out) {
  __shared__ unsigned spk[32], snk[32];
  __shared__ float ssum[4];
  __shared__ int   scnt[4];
  const int tid = threadIdx.x;
  const int a0  = blockIdx.x * 32;

  if (tid < 32) { spk[tid] = 0u; snk[tid] = 0xFFFFFFFFu; }
  __syncthreads();

  {
    const int a    = a0 + (tid & 31);
    const int part = tid >> 5;           // 0..7 -> slots part*16 .. part*16+15
    unsigned p = 0u, n = 0xFFFFFFFFu;
#pragma unroll
    for (int s = 0; s < 16; ++s) {
      size_t idx = (size_t)(part * 16 + s) * B_N + a;
      unsigned pv = ppart[idx];
      unsigned nv = npart[idx];
      p = p > pv ? p : pv;
      n = n < nv ? n : nv;
    }
    atomicMax(&spk[tid & 31], p);        // LDS atomics: cheap, 8-way
    atomicMin(&snk[tid & 31], n);
  }
  __syncthreads();

  const int w = tid >> 6, lane = tid & 63;
  float lsum = 0.f; int lcnt = 0;
#pragma unroll
  for (int it = 0; it < 8; ++it) {
    int al = w * 8 + it;                 // 0..31
    int a  = a0 + al;
    unsigned p = spk[al];
    unsigned n = snk[al];
    bool valid = (p != 0u) && (n != 0xFFFFFFFFu);
    int  pidx = valid ? (int)(p & 8191u) : 0;
    int  nidx = valid ? (int)(n & 8191u) : 0;

    float4 xa = *reinterpret_cast<const float4*>(x + (size_t)a * D_K + lane * 4);
    float4 xp = *reinterpret_cast<const float4*>(x + (size_t)pidx * D_K + lane * 4);
    float4 xn = *reinterpret_cast<const float4*>(x + (size_t)nidx * D_K + lane * 4);
    float dx, sp = 0.f, sn = 0.f;
    dx = xa.x - xp.x + 1e-6f; sp = fmaf(dx, dx, sp);
    dx = xa.y - xp.y + 1e-6f; sp = fmaf(dx, dx, sp);
    dx = xa.z - xp.z + 1e-6f; sp = fmaf(dx, dx, sp);
    dx = xa.w - xp.w + 1e-6f; sp = fmaf(dx, dx, sp);
    dx = xa.x - xn.x + 1e-6f; sn = fmaf(dx, dx, sn);
    dx = xa.y - xn.y + 1e-6f; sn = fmaf(dx, dx, sn);
    dx = xa.z - xn.z + 1e-6f; sn = fmaf(dx, dx, sn);
    dx = xa.w - xn.w + 1e-6f; sn = fmaf(dx, dx, sn);
#pragma unroll
    for (int o = 32; o > 0; o >>= 1) {
      sp += __shfl_down(sp, o, 64);
      sn += __shfl_down(sn, o, 64);
    }
    if (lane == 0 && valid) {
      float per = sqrtf(sp) - sqrtf(sn) + 0.3f;
      if (per > 0.f) lsum += per;
      lcnt += 1;
    }
  }
  if (lane == 0) { ssum[w] = lsum; scnt[w] = lcnt; }
  __syncthreads();
  if (tid == 0) {
    atomicAdd(sum, ssum[0] + ssum[1] + ssum[2] + ssum[3]);
    atomicAdd(cnt, scnt[0] + scnt[1] + scnt[2] + scnt[3]);
    __threadfence();
    int prev = atomicAdd(done, 1);
    if (prev == gridDim.x - 1) {
      float s = atomicAdd(sum, 0.f);
      int   cc = atomicAdd(cnt, 0);
      if (cc < 1) cc = 1;
      out[0] = s / (float)cc;
    }
  }
}

extern "C" void kernel_launch(void* const* d_in, const int* in_sizes, int n_in,
                              void* d_out, int out_size, void* d_ws, size_t ws_size,
                              hipStream_t stream) {
  const float* x   = (const float*)d_in[0];
  const int*   lab = (const int*)d_in[1];
  float*       out = (float*)d_out;

  char* ws = (char*)d_ws;
  unsigned short* xhf = (unsigned short*)ws;                      // 4 MB
  float* sqq = (float*)(ws + (size_t)4608 * 1024);                // 32 KB
  char*  pb = ws + (size_t)4608 * 1024 + 65536;
  size_t seg = (size_t)128 * B_N * 4;                             // 4 MB each
  unsigned* ppart = (unsigned*)(pb);
  unsigned* npart = (unsigned*)(pb + seg);
  float* sum  = (float*)(pb + 2 * seg);
  int*   cnt  = (int*)(sum + 1);
  int*   done = (int*)(sum + 2);

  k_split<<<B_N / 16, 256, 0, stream>>>(x, xhf, sqq, sum, cnt, done);
  k_mine16<<<4160, 256, 0, stream>>>(xhf, lab, sqq, ppart, npart);
  k_finish<<<B_N / 32, 256, 0, stream>>>(x, ppart, npart, sum, cnt, done, out);
}